// Round 1
// baseline (436.605 us; speedup 1.0000x reference)
//
#include <hip/hip_runtime.h>

#define NEG_SLOPE 0.2f

__device__ __forceinline__ float bf2f(unsigned short u) {
    union { unsigned int u32; float f; } c;
    c.u32 = ((unsigned int)u) << 16;
    return c.f;
}
__device__ __forceinline__ unsigned short f2bf(float f) {
    union { float f; unsigned int u32; } c; c.f = f;
    unsigned int b = c.u32;
    b += 0x7fffu + ((b >> 16) & 1u);   // round-to-nearest-even
    return (unsigned short)(b >> 16);
}

// ---------------------------------------------------------------------------
// K1: ft[M,256] = feat[M,256] @ W[256,256], stored as bf16.
// 128x128 tile, 256 threads, 8x8 per thread, BK=16.
// ---------------------------------------------------------------------------
__global__ __launch_bounds__(256) void k_gemm(
    const float* __restrict__ A, const float* __restrict__ B,
    unsigned short* __restrict__ C, int M)
{
    __shared__ float As[16][132];   // transposed: As[k][m]
    __shared__ float Bs[16][132];   // Bs[k][n]
    const int tid = threadIdx.x;
    const int tx = tid & 15, ty = tid >> 4;
    const int m0 = blockIdx.x * 128;
    const int n0 = blockIdx.y * 128;

    float acc[8][8];
#pragma unroll
    for (int i = 0; i < 8; ++i)
#pragma unroll
        for (int j = 0; j < 8; ++j) acc[i][j] = 0.f;

    const int arow = tid >> 2, af4 = tid & 3;   // A: 64 rows/pass, 4 float4 per row
    const int brow = tid >> 5, bf4 = tid & 31;  // B: 8 rows/pass, 32 float4 per row

    for (int kt = 0; kt < 16; ++kt) {
        const int k0 = kt * 16;
#pragma unroll
        for (int p = 0; p < 2; ++p) {
            int row = p * 64 + arow;
            float4 v = make_float4(0.f, 0.f, 0.f, 0.f);
            if (m0 + row < M)
                v = *(const float4*)&A[(size_t)(m0 + row) * 256 + k0 + af4 * 4];
            As[af4 * 4 + 0][row] = v.x;
            As[af4 * 4 + 1][row] = v.y;
            As[af4 * 4 + 2][row] = v.z;
            As[af4 * 4 + 3][row] = v.w;
        }
#pragma unroll
        for (int p = 0; p < 2; ++p) {
            int krow = p * 8 + brow;
            float4 v = *(const float4*)&B[(size_t)(k0 + krow) * 256 + n0 + bf4 * 4];
            *(float4*)&Bs[krow][bf4 * 4] = v;
        }
        __syncthreads();
#pragma unroll
        for (int k = 0; k < 16; ++k) {
            float a[8], b[8];
            *(float4*)&a[0] = *(const float4*)&As[k][ty * 8];
            *(float4*)&a[4] = *(const float4*)&As[k][ty * 8 + 4];
            *(float4*)&b[0] = *(const float4*)&Bs[k][tx * 4];
            *(float4*)&b[4] = *(const float4*)&Bs[k][64 + tx * 4];
#pragma unroll
            for (int i = 0; i < 8; ++i)
#pragma unroll
                for (int j = 0; j < 8; ++j)
                    acc[i][j] = fmaf(a[i], b[j], acc[i][j]);
        }
        __syncthreads();
    }

#pragma unroll
    for (int i = 0; i < 8; ++i) {
        int row = m0 + ty * 8 + i;
        if (row < M) {
#pragma unroll
            for (int j = 0; j < 2; ++j) {
                int col = n0 + j * 64 + tx * 4;
                ushort4 o;
                o.x = f2bf(acc[i][j * 4 + 0]);
                o.y = f2bf(acc[i][j * 4 + 1]);
                o.z = f2bf(acc[i][j * 4 + 2]);
                o.w = f2bf(acc[i][j * 4 + 3]);
                *(ushort4*)&C[(size_t)row * 256 + col] = o;
            }
        }
    }
}

// ---------------------------------------------------------------------------
// K2: per-node attention logits el[n,h] = sum_d ft[n,h,d]*attn_l[h,d], er same.
// One wave per node; lane covers 4 consecutive cols; 8-lane segmented reduce.
// ---------------------------------------------------------------------------
__global__ __launch_bounds__(256) void k_elr(
    const unsigned short* __restrict__ ft,
    const float* __restrict__ attn_l, const float* __restrict__ attn_r,
    float* __restrict__ el, float* __restrict__ er, int N)
{
    const int tid = threadIdx.x;
    const int lane = tid & 63;
    const int n = blockIdx.x * 4 + (tid >> 6);
    if (n >= N) return;
    const int h = lane >> 3;
    const int c = lane * 4;      // flat col in [0,256): h*32 + d
    ushort4 v = *(const ushort4*)&ft[(size_t)n * 256 + c];
    float4 al = *(const float4*)&attn_l[c];
    float4 ar = *(const float4*)&attn_r[c];
    float f0 = bf2f(v.x), f1 = bf2f(v.y), f2 = bf2f(v.z), f3 = bf2f(v.w);
    float pl = f0 * al.x + f1 * al.y + f2 * al.z + f3 * al.w;
    float pr = f0 * ar.x + f1 * ar.y + f2 * ar.z + f3 * ar.w;
#pragma unroll
    for (int off = 1; off <= 4; off <<= 1) {
        pl += __shfl_xor(pl, off);
        pr += __shfl_xor(pr, off);
    }
    if ((lane & 7) == 0) {
        el[n * 8 + h] = pl;
        er[n * 8 + h] = pr;
    }
}

// ---------------------------------------------------------------------------
// CSR build: zero, histogram, ticket-alloc (rows need not be id-ordered),
// scatter src ids.
// ---------------------------------------------------------------------------
__global__ __launch_bounds__(256) void k_zero(int* __restrict__ deg, int* __restrict__ counter, int N)
{
    int n = blockIdx.x * 256 + threadIdx.x;
    if (n < N) deg[n] = 0;
    if (n == 0) *counter = 0;
}
__global__ __launch_bounds__(256) void k_hist(const int* __restrict__ dst, int* __restrict__ deg, int E)
{
    int e = blockIdx.x * 256 + threadIdx.x;
    if (e < E) atomicAdd(&deg[dst[e]], 1);
}
__global__ __launch_bounds__(256) void k_alloc(const int* __restrict__ deg,
    int* __restrict__ row_off, int* __restrict__ cur, int* counter, int N)
{
    int n = blockIdx.x * 256 + threadIdx.x;
    if (n < N) {
        int d = deg[n];
        int s = atomicAdd(counter, d);
        row_off[n] = s;
        cur[n] = s;
    }
}
__global__ __launch_bounds__(256) void k_scatter(const int* __restrict__ src,
    const int* __restrict__ dst, int* __restrict__ cur, int* __restrict__ perm_src, int E)
{
    int e = blockIdx.x * 256 + threadIdx.x;
    if (e < E) {
        int p = atomicAdd(&cur[dst[e]], 1);
        perm_src[p] = src[e];
    }
}

// ---------------------------------------------------------------------------
// K3: per-dst aggregation. One wave per node; lane covers 4 of 256 cols.
// w = exp(leakyrelu(el[src]+er[dst])) recomputed on the fly (max-free softmax
// is exact: a = w/sum_w). Unroll x4 for memory-level parallelism.
// ---------------------------------------------------------------------------
__global__ __launch_bounds__(256) void k_agg(
    const unsigned short* __restrict__ ft,
    const float* __restrict__ el, const float* __restrict__ er,
    const int* __restrict__ row_off, const int* __restrict__ deg,
    const int* __restrict__ perm_src,
    const float* __restrict__ bias, float* __restrict__ out, int N)
{
    const int tid = threadIdx.x;
    const int lane = tid & 63;
    const int n = blockIdx.x * 4 + (tid >> 6);
    if (n >= N) return;
    const int h = lane >> 3;
    const int col = lane * 4;    // h*32 + dsub
    const float erh = er[n * 8 + h];
    const int start = row_off[n];
    const int cnt = deg[n];

    float a0 = 0.f, a1 = 0.f, a2 = 0.f, a3 = 0.f, sw = 0.f;

    int j = 0;
    for (; j + 3 < cnt; j += 4) {
        int sv0 = perm_src[start + j + 0];
        int sv1 = perm_src[start + j + 1];
        int sv2 = perm_src[start + j + 2];
        int sv3 = perm_src[start + j + 3];
        float e0 = el[sv0 * 8 + h] + erh;
        float e1 = el[sv1 * 8 + h] + erh;
        float e2 = el[sv2 * 8 + h] + erh;
        float e3 = el[sv3 * 8 + h] + erh;
        ushort4 f0 = *(const ushort4*)&ft[(size_t)sv0 * 256 + col];
        ushort4 f1 = *(const ushort4*)&ft[(size_t)sv1 * 256 + col];
        ushort4 f2 = *(const ushort4*)&ft[(size_t)sv2 * 256 + col];
        ushort4 f3 = *(const ushort4*)&ft[(size_t)sv3 * 256 + col];
        e0 = e0 > 0.f ? e0 : NEG_SLOPE * e0;
        e1 = e1 > 0.f ? e1 : NEG_SLOPE * e1;
        e2 = e2 > 0.f ? e2 : NEG_SLOPE * e2;
        e3 = e3 > 0.f ? e3 : NEG_SLOPE * e3;
        float w0 = __expf(e0), w1 = __expf(e1), w2 = __expf(e2), w3 = __expf(e3);
        a0 = fmaf(w0, bf2f(f0.x), a0); a1 = fmaf(w0, bf2f(f0.y), a1);
        a2 = fmaf(w0, bf2f(f0.z), a2); a3 = fmaf(w0, bf2f(f0.w), a3);
        a0 = fmaf(w1, bf2f(f1.x), a0); a1 = fmaf(w1, bf2f(f1.y), a1);
        a2 = fmaf(w1, bf2f(f1.z), a2); a3 = fmaf(w1, bf2f(f1.w), a3);
        a0 = fmaf(w2, bf2f(f2.x), a0); a1 = fmaf(w2, bf2f(f2.y), a1);
        a2 = fmaf(w2, bf2f(f2.z), a2); a3 = fmaf(w2, bf2f(f2.w), a3);
        a0 = fmaf(w3, bf2f(f3.x), a0); a1 = fmaf(w3, bf2f(f3.y), a1);
        a2 = fmaf(w3, bf2f(f3.z), a2); a3 = fmaf(w3, bf2f(f3.w), a3);
        sw += (w0 + w1) + (w2 + w3);
    }
    for (; j < cnt; ++j) {
        int sv = perm_src[start + j];
        float e = el[sv * 8 + h] + erh;
        e = e > 0.f ? e : NEG_SLOPE * e;
        float w = __expf(e);
        ushort4 f = *(const ushort4*)&ft[(size_t)sv * 256 + col];
        a0 = fmaf(w, bf2f(f.x), a0);
        a1 = fmaf(w, bf2f(f.y), a1);
        a2 = fmaf(w, bf2f(f.z), a2);
        a3 = fmaf(w, bf2f(f.w), a3);
        sw += w;
    }

    float inv = cnt > 0 ? 1.f / sw : 0.f;
    float4 b = *(const float4*)&bias[col];
    float4 o;
    o.x = a0 * inv + b.x;
    o.y = a1 * inv + b.y;
    o.z = a2 * inv + b.z;
    o.w = a3 * inv + b.w;
    *(float4*)&out[(size_t)n * 256 + col] = o;
}

// ---------------------------------------------------------------------------
extern "C" void kernel_launch(void* const* d_in, const int* in_sizes, int n_in,
                              void* d_out, int out_size, void* d_ws, size_t ws_size,
                              hipStream_t stream)
{
    const float* feat   = (const float*)d_in[0];
    const float* W      = (const float*)d_in[1];
    const float* attn_l = (const float*)d_in[2];
    const float* attn_r = (const float*)d_in[3];
    const float* bias   = (const float*)d_in[4];
    const int*   src    = (const int*)d_in[5];
    const int*   dst    = (const int*)d_in[6];
    const int N = in_sizes[0] / 256;
    const int E = in_sizes[5];
    float* out = (float*)d_out;

    char* ws = (char*)d_ws;
    size_t off = 0;
    auto wsalloc = [&](size_t bytes) -> char* {
        char* p = ws + off;
        off = (off + bytes + 255) & ~(size_t)255;
        return p;
    };
    unsigned short* ft   = (unsigned short*)wsalloc((size_t)N * 256 * 2); // 25.6 MB
    float* el            = (float*)wsalloc((size_t)N * 8 * 4);
    float* er            = (float*)wsalloc((size_t)N * 8 * 4);
    int* deg             = (int*)wsalloc((size_t)N * 4);
    int* row_off         = (int*)wsalloc((size_t)N * 4);
    int* cur             = (int*)wsalloc((size_t)N * 4);
    int* perm_src        = (int*)wsalloc((size_t)E * 4);                  // 6.4 MB
    int* counter         = (int*)wsalloc(256);
    (void)ws_size; (void)n_in; (void)out_size;

    dim3 gg((N + 127) / 128, 2);
    k_gemm<<<gg, 256, 0, stream>>>(feat, W, ft, N);
    k_zero<<<(N + 255) / 256, 256, 0, stream>>>(deg, counter, N);
    k_elr<<<(N + 3) / 4, 256, 0, stream>>>(ft, attn_l, attn_r, el, er, N);
    k_hist<<<(E + 255) / 256, 256, 0, stream>>>(dst, deg, E);
    k_alloc<<<(N + 255) / 256, 256, 0, stream>>>(deg, row_off, cur, counter, N);
    k_scatter<<<(E + 255) / 256, 256, 0, stream>>>(src, dst, cur, perm_src, E);
    k_agg<<<(N + 3) / 4, 256, 0, stream>>>(ft, el, er, row_off, deg, perm_src, bias, out, N);
}

// Round 2
// 268.583 us; speedup vs baseline: 1.6256x; 1.6256x over previous
//
#include <hip/hip_runtime.h>

#define NEG_SLOPE 0.2f

#define BUK_SHIFT 7
#define BUK_NODES 128
#define BUK_CAP   5120
#define MAX_NBUK  512
#define OVER_CAP  4096

__device__ __forceinline__ float bf2f(unsigned short u) {
    union { unsigned int u32; float f; } c;
    c.u32 = ((unsigned int)u) << 16;
    return c.f;
}
__device__ __forceinline__ unsigned short f2bf(float f) {
    union { float f; unsigned int u32; } c; c.f = f;
    unsigned int b = c.u32;
    b += 0x7fffu + ((b >> 16) & 1u);   // round-to-nearest-even
    return (unsigned short)(b >> 16);
}

// ---------------------------------------------------------------------------
// K1: ft[M,256] = feat[M,256] @ W[256,256], stored as bf16.
// 128x128 tile, 256 threads, 8x8 per thread, BK=16.
// ---------------------------------------------------------------------------
__global__ __launch_bounds__(256) void k_gemm(
    const float* __restrict__ A, const float* __restrict__ B,
    unsigned short* __restrict__ C, int M)
{
    __shared__ float As[16][132];   // transposed: As[k][m]
    __shared__ float Bs[16][132];   // Bs[k][n]
    const int tid = threadIdx.x;
    const int tx = tid & 15, ty = tid >> 4;
    const int m0 = blockIdx.x * 128;
    const int n0 = blockIdx.y * 128;

    float acc[8][8];
#pragma unroll
    for (int i = 0; i < 8; ++i)
#pragma unroll
        for (int j = 0; j < 8; ++j) acc[i][j] = 0.f;

    const int arow = tid >> 2, af4 = tid & 3;
    const int brow = tid >> 5, bf4 = tid & 31;

    for (int kt = 0; kt < 16; ++kt) {
        const int k0 = kt * 16;
#pragma unroll
        for (int p = 0; p < 2; ++p) {
            int row = p * 64 + arow;
            float4 v = make_float4(0.f, 0.f, 0.f, 0.f);
            if (m0 + row < M)
                v = *(const float4*)&A[(size_t)(m0 + row) * 256 + k0 + af4 * 4];
            As[af4 * 4 + 0][row] = v.x;
            As[af4 * 4 + 1][row] = v.y;
            As[af4 * 4 + 2][row] = v.z;
            As[af4 * 4 + 3][row] = v.w;
        }
#pragma unroll
        for (int p = 0; p < 2; ++p) {
            int krow = p * 8 + brow;
            float4 v = *(const float4*)&B[(size_t)(k0 + krow) * 256 + n0 + bf4 * 4];
            *(float4*)&Bs[krow][bf4 * 4] = v;
        }
        __syncthreads();
#pragma unroll
        for (int k = 0; k < 16; ++k) {
            float a[8], b[8];
            *(float4*)&a[0] = *(const float4*)&As[k][ty * 8];
            *(float4*)&a[4] = *(const float4*)&As[k][ty * 8 + 4];
            *(float4*)&b[0] = *(const float4*)&Bs[k][tx * 4];
            *(float4*)&b[4] = *(const float4*)&Bs[k][64 + tx * 4];
#pragma unroll
            for (int i = 0; i < 8; ++i)
#pragma unroll
                for (int j = 0; j < 8; ++j)
                    acc[i][j] = fmaf(a[i], b[j], acc[i][j]);
        }
        __syncthreads();
    }

#pragma unroll
    for (int i = 0; i < 8; ++i) {
        int row = m0 + ty * 8 + i;
        if (row < M) {
#pragma unroll
            for (int j = 0; j < 2; ++j) {
                int col = n0 + j * 64 + tx * 4;
                ushort4 o;
                o.x = f2bf(acc[i][j * 4 + 0]);
                o.y = f2bf(acc[i][j * 4 + 1]);
                o.z = f2bf(acc[i][j * 4 + 2]);
                o.w = f2bf(acc[i][j * 4 + 3]);
                *(ushort4*)&C[(size_t)row * 256 + col] = o;
            }
        }
    }
}

// ---------------------------------------------------------------------------
// K2: per-node attention logits el[n,h], er[n,h].
// ---------------------------------------------------------------------------
__global__ __launch_bounds__(256) void k_elr(
    const unsigned short* __restrict__ ft,
    const float* __restrict__ attn_l, const float* __restrict__ attn_r,
    float* __restrict__ el, float* __restrict__ er, int N)
{
    const int tid = threadIdx.x;
    const int lane = tid & 63;
    const int n = blockIdx.x * 4 + (tid >> 6);
    if (n >= N) return;
    const int h = lane >> 3;
    const int c = lane * 4;
    ushort4 v = *(const ushort4*)&ft[(size_t)n * 256 + c];
    float4 al = *(const float4*)&attn_l[c];
    float4 ar = *(const float4*)&attn_r[c];
    float f0 = bf2f(v.x), f1 = bf2f(v.y), f2 = bf2f(v.z), f3 = bf2f(v.w);
    float pl = f0 * al.x + f1 * al.y + f2 * al.z + f3 * al.w;
    float pr = f0 * ar.x + f1 * ar.y + f2 * ar.z + f3 * ar.w;
#pragma unroll
    for (int off = 1; off <= 4; off <<= 1) {
        pl += __shfl_xor(pl, off);
        pr += __shfl_xor(pr, off);
    }
    if ((lane & 7) == 0) {
        el[n * 8 + h] = pl;
        er[n * 8 + h] = pr;
    }
}

// ---------------------------------------------------------------------------
// K0: zero bucket counters + overflow counter.
// ---------------------------------------------------------------------------
__global__ __launch_bounds__(256) void k_zero(int* __restrict__ bucket_cnt, int nbuk,
                                              int* __restrict__ over_cnt)
{
    int i = blockIdx.x * 256 + threadIdx.x;
    if (i < nbuk) bucket_cnt[i] = 0;
    if (i == 0) *over_cnt = 0;
}

// ---------------------------------------------------------------------------
// K3a: two-level binning pass 1 — scatter (src,dst) pairs into per-bucket
// regions (bucket = dst>>7). LDS histogram -> ONE global atomic per
// (block,bin) -> LDS-ranked writes. Per-block per-bucket chunks are ~10
// contiguous edges, so L2 lines fill before eviction (full-line writeback).
// 512 threads x 8 edges = 4096 edges/block.
// ---------------------------------------------------------------------------
__global__ __launch_bounds__(512) void k_bucket(
    const int* __restrict__ src, const int* __restrict__ dst, int E, int nbuk,
    int* __restrict__ bucket_cnt, int2* __restrict__ bucket_edges,
    int* __restrict__ over_cnt, int2* __restrict__ over_edges)
{
    __shared__ int lhist[MAX_NBUK];
    __shared__ int lbase[MAX_NBUK];
    __shared__ int lcur[MAX_NBUK];
    const int tid = threadIdx.x;
    for (int i = tid; i < nbuk; i += 512) lhist[i] = 0;
    __syncthreads();

    const int e0 = blockIdx.x * 4096;
    // pass 1: local histogram
#pragma unroll
    for (int p = 0; p < 8; ++p) {
        int e = e0 + p * 512 + tid;
        if (e < E) atomicAdd(&lhist[dst[e] >> BUK_SHIFT], 1);
    }
    __syncthreads();
    // claim global ranges, one atomic per non-empty bin
    for (int i = tid; i < nbuk; i += 512) {
        int c = lhist[i];
        lbase[i] = (c > 0) ? atomicAdd(&bucket_cnt[i], c) : 0;
        lcur[i] = 0;
    }
    __syncthreads();
    // pass 2: re-read edges (L2-hot) and write pairs
#pragma unroll
    for (int p = 0; p < 8; ++p) {
        int e = e0 + p * 512 + tid;
        if (e < E) {
            int d = dst[e];
            int s = src[e];
            int bin = d >> BUK_SHIFT;
            int r = atomicAdd(&lcur[bin], 1);
            int pos = lbase[bin] + r;
            if (pos < BUK_CAP) {
                bucket_edges[(size_t)bin * BUK_CAP + pos] = make_int2(s, d);
            } else {
                int oi = atomicAdd(over_cnt, 1);
                if (oi < OVER_CAP) over_edges[oi] = make_int2(s, d);
            }
        }
    }
}

// ---------------------------------------------------------------------------
// K3b: per-bucket CSR finalize. One block per bucket: LDS histogram over the
// 128 local nodes, serial scan, write deg/row_start, scatter src ids within
// the bucket's L2-resident region.
// ---------------------------------------------------------------------------
__global__ __launch_bounds__(256) void k_csr(
    const int2* __restrict__ bucket_edges, const int* __restrict__ bucket_cnt,
    int N, int* __restrict__ deg, int* __restrict__ row_start,
    int* __restrict__ perm_src)
{
    __shared__ int hist[BUK_NODES];
    __shared__ int pfx[BUK_NODES];
    __shared__ int curs[BUK_NODES];
    const int bu = blockIdx.x;
    const int tid = threadIdx.x;
    const int cnt = min(bucket_cnt[bu], BUK_CAP);
    const int node0 = bu << BUK_SHIFT;
    if (tid < BUK_NODES) hist[tid] = 0;
    __syncthreads();
    for (int i = tid; i < cnt; i += 256) {
        int2 ed = bucket_edges[(size_t)bu * BUK_CAP + i];
        atomicAdd(&hist[ed.y & (BUK_NODES - 1)], 1);
    }
    __syncthreads();
    if (tid == 0) {
        int s = 0;
#pragma unroll
        for (int i = 0; i < BUK_NODES; ++i) { pfx[i] = s; s += hist[i]; }
    }
    __syncthreads();
    if (tid < BUK_NODES) {
        int n = node0 + tid;
        if (n < N) {
            deg[n] = hist[tid];
            row_start[n] = bu * BUK_CAP + pfx[tid];
        }
        curs[tid] = pfx[tid];
    }
    __syncthreads();
    for (int i = tid; i < cnt; i += 256) {
        int2 ed = bucket_edges[(size_t)bu * BUK_CAP + i];
        int r = atomicAdd(&curs[ed.y & (BUK_NODES - 1)], 1);
        perm_src[(size_t)bu * BUK_CAP + r] = ed.x;
    }
}

// ---------------------------------------------------------------------------
// K4: per-dst aggregation. One wave per node; lane covers 4 of 256 cols.
// w = exp(leakyrelu(el[src]+er[dst])) on the fly; max-free softmax is exact.
// ---------------------------------------------------------------------------
__global__ __launch_bounds__(256) void k_agg(
    const unsigned short* __restrict__ ft,
    const float* __restrict__ el, const float* __restrict__ er,
    const int* __restrict__ row_start, const int* __restrict__ deg,
    const int* __restrict__ perm_src,
    const float* __restrict__ bias, float* __restrict__ out, int N,
    const int* __restrict__ over_cnt, const int2* __restrict__ over_edges)
{
    const int tid = threadIdx.x;
    const int lane = tid & 63;
    const int n = blockIdx.x * 4 + (tid >> 6);
    if (n >= N) return;
    const int h = lane >> 3;
    const int col = lane * 4;
    const float erh = er[n * 8 + h];
    const int start = row_start[n];
    const int cnt = deg[n];

    float a0 = 0.f, a1 = 0.f, a2 = 0.f, a3 = 0.f, sw = 0.f;

    int j = 0;
    for (; j + 3 < cnt; j += 4) {
        int sv0 = perm_src[start + j + 0];
        int sv1 = perm_src[start + j + 1];
        int sv2 = perm_src[start + j + 2];
        int sv3 = perm_src[start + j + 3];
        float e0 = el[sv0 * 8 + h] + erh;
        float e1 = el[sv1 * 8 + h] + erh;
        float e2 = el[sv2 * 8 + h] + erh;
        float e3 = el[sv3 * 8 + h] + erh;
        ushort4 f0 = *(const ushort4*)&ft[(size_t)sv0 * 256 + col];
        ushort4 f1 = *(const ushort4*)&ft[(size_t)sv1 * 256 + col];
        ushort4 f2 = *(const ushort4*)&ft[(size_t)sv2 * 256 + col];
        ushort4 f3 = *(const ushort4*)&ft[(size_t)sv3 * 256 + col];
        e0 = e0 > 0.f ? e0 : NEG_SLOPE * e0;
        e1 = e1 > 0.f ? e1 : NEG_SLOPE * e1;
        e2 = e2 > 0.f ? e2 : NEG_SLOPE * e2;
        e3 = e3 > 0.f ? e3 : NEG_SLOPE * e3;
        float w0 = __expf(e0), w1 = __expf(e1), w2 = __expf(e2), w3 = __expf(e3);
        a0 = fmaf(w0, bf2f(f0.x), a0); a1 = fmaf(w0, bf2f(f0.y), a1);
        a2 = fmaf(w0, bf2f(f0.z), a2); a3 = fmaf(w0, bf2f(f0.w), a3);
        a0 = fmaf(w1, bf2f(f1.x), a0); a1 = fmaf(w1, bf2f(f1.y), a1);
        a2 = fmaf(w1, bf2f(f1.z), a2); a3 = fmaf(w1, bf2f(f1.w), a3);
        a0 = fmaf(w2, bf2f(f2.x), a0); a1 = fmaf(w2, bf2f(f2.y), a1);
        a2 = fmaf(w2, bf2f(f2.z), a2); a3 = fmaf(w2, bf2f(f2.w), a3);
        a0 = fmaf(w3, bf2f(f3.x), a0); a1 = fmaf(w3, bf2f(f3.y), a1);
        a2 = fmaf(w3, bf2f(f3.z), a2); a3 = fmaf(w3, bf2f(f3.w), a3);
        sw += (w0 + w1) + (w2 + w3);
    }
    for (; j < cnt; ++j) {
        int sv = perm_src[start + j];
        float e = el[sv * 8 + h] + erh;
        e = e > 0.f ? e : NEG_SLOPE * e;
        float w = __expf(e);
        ushort4 f = *(const ushort4*)&ft[(size_t)sv * 256 + col];
        a0 = fmaf(w, bf2f(f.x), a0);
        a1 = fmaf(w, bf2f(f.y), a1);
        a2 = fmaf(w, bf2f(f.z), a2);
        a3 = fmaf(w, bf2f(f.w), a3);
        sw += w;
    }

    // overflow fallback: scan spill list (practically always empty)
    int oc = *over_cnt;
    if (oc > 0) {
        oc = min(oc, OVER_CAP);
        for (int i = 0; i < oc; ++i) {
            int2 ed = over_edges[i];
            if (ed.y == n) {
                float e = el[ed.x * 8 + h] + erh;
                e = e > 0.f ? e : NEG_SLOPE * e;
                float w = __expf(e);
                ushort4 f = *(const ushort4*)&ft[(size_t)ed.x * 256 + col];
                a0 = fmaf(w, bf2f(f.x), a0);
                a1 = fmaf(w, bf2f(f.y), a1);
                a2 = fmaf(w, bf2f(f.z), a2);
                a3 = fmaf(w, bf2f(f.w), a3);
                sw += w;
            }
        }
    }

    float inv = sw != 0.f ? 1.f / sw : 0.f;
    float4 b = *(const float4*)&bias[col];
    float4 o;
    o.x = a0 * inv + b.x;
    o.y = a1 * inv + b.y;
    o.z = a2 * inv + b.z;
    o.w = a3 * inv + b.w;
    *(float4*)&out[(size_t)n * 256 + col] = o;
}

// ---------------------------------------------------------------------------
extern "C" void kernel_launch(void* const* d_in, const int* in_sizes, int n_in,
                              void* d_out, int out_size, void* d_ws, size_t ws_size,
                              hipStream_t stream)
{
    const float* feat   = (const float*)d_in[0];
    const float* W      = (const float*)d_in[1];
    const float* attn_l = (const float*)d_in[2];
    const float* attn_r = (const float*)d_in[3];
    const float* bias   = (const float*)d_in[4];
    const int*   src    = (const int*)d_in[5];
    const int*   dst    = (const int*)d_in[6];
    const int N = in_sizes[0] / 256;
    const int E = in_sizes[5];
    const int nbuk = (N + BUK_NODES - 1) >> BUK_SHIFT;
    float* out = (float*)d_out;

    char* ws = (char*)d_ws;
    size_t off = 0;
    auto wsalloc = [&](size_t bytes) -> char* {
        char* p = ws + off;
        off = (off + bytes + 255) & ~(size_t)255;
        return p;
    };
    unsigned short* ft   = (unsigned short*)wsalloc((size_t)N * 256 * 2);       // 25.6 MB
    float* el            = (float*)wsalloc((size_t)N * 8 * 4);                  // 1.6 MB
    float* er            = (float*)wsalloc((size_t)N * 8 * 4);                  // 1.6 MB
    int* deg             = (int*)wsalloc((size_t)N * 4);                        // 0.2 MB
    int* row_start       = (int*)wsalloc((size_t)N * 4);                        // 0.2 MB
    int* bucket_cnt      = (int*)wsalloc((size_t)nbuk * 4);
    int2* bucket_edges   = (int2*)wsalloc((size_t)nbuk * BUK_CAP * 8);          // 16 MB
    int* perm_src        = (int*)wsalloc((size_t)nbuk * BUK_CAP * 4);           // 8 MB
    int* over_cnt        = (int*)wsalloc(256);
    int2* over_edges     = (int2*)wsalloc((size_t)OVER_CAP * 8);
    (void)ws_size; (void)n_in; (void)out_size;

    dim3 gg((N + 127) / 128, 2);
    k_gemm<<<gg, 256, 0, stream>>>(feat, W, ft, N);
    k_zero<<<(nbuk + 255) / 256, 256, 0, stream>>>(bucket_cnt, nbuk, over_cnt);
    k_bucket<<<(E + 4095) / 4096, 512, 0, stream>>>(src, dst, E, nbuk,
        bucket_cnt, bucket_edges, over_cnt, over_edges);
    k_elr<<<(N + 3) / 4, 256, 0, stream>>>(ft, attn_l, attn_r, el, er, N);
    k_csr<<<nbuk, 256, 0, stream>>>(bucket_edges, bucket_cnt, N, deg, row_start, perm_src);
    k_agg<<<(N + 3) / 4, 256, 0, stream>>>(ft, el, er, row_start, deg, perm_src,
        bias, out, N, over_cnt, over_edges);
}

// Round 3
// 253.768 us; speedup vs baseline: 1.7205x; 1.0584x over previous
//
#include <hip/hip_runtime.h>

#define NEG_SLOPE 0.2f
#define LOG2E 1.44269504088896340736f

#define BUK_SHIFT 7
#define BUK_NODES 128
#define BUK_CAP   5120
#define MAX_NBUK  512
#define OVER_CAP  4096

typedef __attribute__((ext_vector_type(8))) short short8v;
typedef __attribute__((ext_vector_type(4))) float float4v;

__device__ __forceinline__ float bf2f(unsigned short u) {
    union { unsigned int u32; float f; } c;
    c.u32 = ((unsigned int)u) << 16;
    return c.f;
}
__device__ __forceinline__ unsigned short f2bf(float f) {
    union { float f; unsigned int u32; } c; c.f = f;
    unsigned int b = c.u32;
    b += 0x7fffu + ((b >> 16) & 1u);   // round-to-nearest-even
    return (unsigned short)(b >> 16);
}
__device__ __forceinline__ float u2f_lo(unsigned int u) {  // low bf16 of dword
    union { unsigned int u32; float f; } c; c.u32 = u << 16; return c.f;
}
__device__ __forceinline__ float u2f_hi(unsigned int u) {  // high bf16 of dword
    union { unsigned int u32; float f; } c; c.u32 = u & 0xFFFF0000u; return c.f;
}

// ---------------------------------------------------------------------------
// K0a: pre-split W (256x256 fp32) into hi/lo bf16 stored in MFMA B-fragment
// order: frag f = ((ks*16+ct)*64+lane), elem j -> W[ks*32+(lane>>4)*8+j][ct*16+(lane&15)].
// 8192 threads, one frag each.
// ---------------------------------------------------------------------------
__global__ __launch_bounds__(256) void k_wsplit(
    const float* __restrict__ W, unsigned short* __restrict__ whi,
    unsigned short* __restrict__ wlo)
{
    const int t = blockIdx.x * 256 + threadIdx.x;   // 0..8191
    const int lane = t & 63;
    const int ct = (t >> 6) & 15;
    const int ks = t >> 10;
    const int col = ct * 16 + (lane & 15);
    const int krow = ks * 32 + (lane >> 4) * 8;
    unsigned short hi[8], lo[8];
#pragma unroll
    for (int j = 0; j < 8; ++j) {
        float v = W[(krow + j) * 256 + col];
        unsigned short h = f2bf(v);
        hi[j] = h;
        lo[j] = f2bf(v - bf2f(h));
    }
#pragma unroll
    for (int j = 0; j < 8; ++j) {
        whi[(size_t)t * 8 + j] = hi[j];
        wlo[(size_t)t * 8 + j] = lo[j];
    }
}

// ---------------------------------------------------------------------------
// K1: ft = feat @ W via split-bf16 MFMA (hi/lo, 3 products ~ fp32-exact).
// 64 rows/block, 4 waves x 16 rows, each wave owns all 256 cols.
// A: fp32 direct global->reg, split in-reg. B: pre-split frags (L2-hot).
// Fused epilogue: el/er (pre-scaled by log2 e) from fp32 acc; ft stored bf16
// via LDS transpose for coalesced writes.
// ---------------------------------------------------------------------------
__global__ __launch_bounds__(256) void k_gemm(
    const float* __restrict__ A,
    const unsigned short* __restrict__ whi, const unsigned short* __restrict__ wlo,
    const float* __restrict__ attn_l, const float* __restrict__ attn_r,
    unsigned short* __restrict__ ft, float* __restrict__ els,
    float* __restrict__ ers, int M)
{
    __shared__ unsigned short sm[4][16][264];
    const int tid = threadIdx.x;
    const int w = tid >> 6, lane = tid & 63;
    const int row0 = blockIdx.x * 64 + w * 16;
    const int arow = row0 + (lane & 15);
    const bool aval = arow < M;
    const float* ap = A + (size_t)arow * 256 + (lane >> 4) * 8;
    const unsigned short* bhip = whi + lane * 8;
    const unsigned short* blop = wlo + lane * 8;

    float4v acc[16];
#pragma unroll
    for (int ct = 0; ct < 16; ++ct) acc[ct] = (float4v){0.f, 0.f, 0.f, 0.f};

#pragma unroll
    for (int ks = 0; ks < 8; ++ks) {
        float av[8];
        if (aval) {
            float4 a0 = *(const float4*)(ap + ks * 32);
            float4 a1 = *(const float4*)(ap + ks * 32 + 4);
            av[0] = a0.x; av[1] = a0.y; av[2] = a0.z; av[3] = a0.w;
            av[4] = a1.x; av[5] = a1.y; av[6] = a1.z; av[7] = a1.w;
        } else {
#pragma unroll
            for (int j = 0; j < 8; ++j) av[j] = 0.f;
        }
        short8v ahi, alo;
#pragma unroll
        for (int j = 0; j < 8; ++j) {
            unsigned short h = f2bf(av[j]);
            ahi[j] = (short)h;
            alo[j] = (short)f2bf(av[j] - bf2f(h));
        }
#pragma unroll
        for (int ct = 0; ct < 16; ++ct) {
            const size_t fo = (size_t)(ks * 8192 + ct * 512);
            short8v bhi = *(const short8v*)(bhip + fo);
            short8v blo = *(const short8v*)(blop + fo);
            acc[ct] = __builtin_amdgcn_mfma_f32_16x16x32_bf16(ahi, bhi, acc[ct], 0, 0, 0);
            acc[ct] = __builtin_amdgcn_mfma_f32_16x16x32_bf16(alo, bhi, acc[ct], 0, 0, 0);
            acc[ct] = __builtin_amdgcn_mfma_f32_16x16x32_bf16(ahi, blo, acc[ct], 0, 0, 0);
        }
    }

    // ---- el/er epilogue (from fp32 acc; C/D layout: col=lane&15, row=(lane>>4)*4+reg)
    const int c = lane & 15;
#pragma unroll
    for (int reg = 0; reg < 4; ++reg) {
        const int row = row0 + (lane >> 4) * 4 + reg;
#pragma unroll
        for (int h = 0; h < 8; ++h) {
            float v0 = acc[2 * h][reg], v1 = acc[2 * h + 1][reg];
            int c0 = h * 32 + c, c1 = h * 32 + 16 + c;
            float pl = v0 * attn_l[c0] + v1 * attn_l[c1];
            float pr = v0 * attn_r[c0] + v1 * attn_r[c1];
#pragma unroll
            for (int off = 1; off <= 8; off <<= 1) {
                pl += __shfl_xor(pl, off);
                pr += __shfl_xor(pr, off);
            }
            if (c == 0 && row < M) {
                els[row * 8 + h] = pl * LOG2E;
                ers[row * 8 + h] = pr * LOG2E;
            }
        }
    }

    // ---- ft store via LDS transpose
#pragma unroll
    for (int ct = 0; ct < 16; ++ct)
#pragma unroll
        for (int reg = 0; reg < 4; ++reg)
            sm[w][(lane >> 4) * 4 + reg][ct * 16 + c] = f2bf(acc[ct][reg]);
    __syncthreads();
#pragma unroll
    for (int it = 0; it < 16; ++it) {
        int unit = it * 64 + lane;          // 1024 ushort4-units per wave
        int row = unit >> 6, q = unit & 63;
        int grow = row0 + row;
        if (grow < M)
            *(ushort4*)(ft + (size_t)grow * 256 + q * 4) = *(ushort4*)&sm[w][row][q * 4];
    }
}

// ---------------------------------------------------------------------------
// K0b: zero bucket counters + overflow counter.
// ---------------------------------------------------------------------------
__global__ __launch_bounds__(256) void k_zero(int* __restrict__ bucket_cnt, int nbuk,
                                              int* __restrict__ over_cnt)
{
    int i = blockIdx.x * 256 + threadIdx.x;
    if (i < nbuk) bucket_cnt[i] = 0;
    if (i == 0) *over_cnt = 0;
}

// ---------------------------------------------------------------------------
// K3a: two-level binning pass 1 — scatter (src,dst) pairs into per-bucket
// regions (bucket = dst>>7). LDS histogram -> one global atomic per
// (block,bin) -> LDS-ranked writes.
// ---------------------------------------------------------------------------
__global__ __launch_bounds__(512) void k_bucket(
    const int* __restrict__ src, const int* __restrict__ dst, int E, int nbuk,
    int* __restrict__ bucket_cnt, int2* __restrict__ bucket_edges,
    int* __restrict__ over_cnt, int2* __restrict__ over_edges)
{
    __shared__ int lhist[MAX_NBUK];
    __shared__ int lbase[MAX_NBUK];
    __shared__ int lcur[MAX_NBUK];
    const int tid = threadIdx.x;
    for (int i = tid; i < nbuk; i += 512) lhist[i] = 0;
    __syncthreads();

    const int e0 = blockIdx.x * 4096;
#pragma unroll
    for (int p = 0; p < 8; ++p) {
        int e = e0 + p * 512 + tid;
        if (e < E) atomicAdd(&lhist[dst[e] >> BUK_SHIFT], 1);
    }
    __syncthreads();
    for (int i = tid; i < nbuk; i += 512) {
        int cc = lhist[i];
        lbase[i] = (cc > 0) ? atomicAdd(&bucket_cnt[i], cc) : 0;
        lcur[i] = 0;
    }
    __syncthreads();
#pragma unroll
    for (int p = 0; p < 8; ++p) {
        int e = e0 + p * 512 + tid;
        if (e < E) {
            int d = dst[e];
            int s = src[e];
            int bin = d >> BUK_SHIFT;
            int r = atomicAdd(&lcur[bin], 1);
            int pos = lbase[bin] + r;
            if (pos < BUK_CAP) {
                bucket_edges[(size_t)bin * BUK_CAP + pos] = make_int2(s, d);
            } else {
                int oi = atomicAdd(over_cnt, 1);
                if (oi < OVER_CAP) over_edges[oi] = make_int2(s, d);
            }
        }
    }
}

// ---------------------------------------------------------------------------
// K3b: per-bucket CSR finalize.
// ---------------------------------------------------------------------------
__global__ __launch_bounds__(256) void k_csr(
    const int2* __restrict__ bucket_edges, const int* __restrict__ bucket_cnt,
    int N, int* __restrict__ deg, int* __restrict__ row_start,
    int* __restrict__ perm_src)
{
    __shared__ int hist[BUK_NODES];
    __shared__ int pfx[BUK_NODES];
    __shared__ int curs[BUK_NODES];
    const int bu = blockIdx.x;
    const int tid = threadIdx.x;
    const int cnt = min(bucket_cnt[bu], BUK_CAP);
    const int node0 = bu << BUK_SHIFT;
    if (tid < BUK_NODES) hist[tid] = 0;
    __syncthreads();
    for (int i = tid; i < cnt; i += 256) {
        int2 ed = bucket_edges[(size_t)bu * BUK_CAP + i];
        atomicAdd(&hist[ed.y & (BUK_NODES - 1)], 1);
    }
    __syncthreads();
    if (tid == 0) {
        int s = 0;
#pragma unroll
        for (int i = 0; i < BUK_NODES; ++i) { pfx[i] = s; s += hist[i]; }
    }
    __syncthreads();
    if (tid < BUK_NODES) {
        int n = node0 + tid;
        if (n < N) {
            deg[n] = hist[tid];
            row_start[n] = bu * BUK_CAP + pfx[tid];
        }
        curs[tid] = pfx[tid];
    }
    __syncthreads();
    for (int i = tid; i < cnt; i += 256) {
        int2 ed = bucket_edges[(size_t)bu * BUK_CAP + i];
        int r = atomicAdd(&curs[ed.y & (BUK_NODES - 1)], 1);
        perm_src[(size_t)bu * BUK_CAP + r] = ed.x;
    }
}

// ---------------------------------------------------------------------------
// K4: per-dst aggregation. One wave per node; lane covers 4 of 256 cols.
// Logits pre-scaled by log2(e) -> w = exp2(lrelu(els[src]+ers[dst])).
// bf16->f32 via dword AND/SHL (2 ops per 2 values).
// ---------------------------------------------------------------------------
__global__ __launch_bounds__(256) void k_agg(
    const unsigned short* __restrict__ ft,
    const float* __restrict__ els, const float* __restrict__ ers,
    const int* __restrict__ row_start, const int* __restrict__ deg,
    const int* __restrict__ perm_src,
    const float* __restrict__ bias, float* __restrict__ out, int N,
    const int* __restrict__ over_cnt, const int2* __restrict__ over_edges)
{
    const int tid = threadIdx.x;
    const int lane = tid & 63;
    const int n = blockIdx.x * 4 + (tid >> 6);
    if (n >= N) return;
    const int h = lane >> 3;
    const int col = lane * 4;
    const float erh = ers[n * 8 + h];
    const int start = row_start[n];
    const int cnt = deg[n];

    float a0 = 0.f, a1 = 0.f, a2 = 0.f, a3 = 0.f, sw = 0.f;

    int j = 0;
    for (; j + 3 < cnt; j += 4) {
        int sv0 = perm_src[start + j + 0];
        int sv1 = perm_src[start + j + 1];
        int sv2 = perm_src[start + j + 2];
        int sv3 = perm_src[start + j + 3];
        float e0 = els[sv0 * 8 + h] + erh;
        float e1 = els[sv1 * 8 + h] + erh;
        float e2 = els[sv2 * 8 + h] + erh;
        float e3 = els[sv3 * 8 + h] + erh;
        uint2 f0 = *(const uint2*)&ft[(size_t)sv0 * 256 + col];
        uint2 f1 = *(const uint2*)&ft[(size_t)sv1 * 256 + col];
        uint2 f2 = *(const uint2*)&ft[(size_t)sv2 * 256 + col];
        uint2 f3 = *(const uint2*)&ft[(size_t)sv3 * 256 + col];
        e0 = e0 > 0.f ? e0 : NEG_SLOPE * e0;
        e1 = e1 > 0.f ? e1 : NEG_SLOPE * e1;
        e2 = e2 > 0.f ? e2 : NEG_SLOPE * e2;
        e3 = e3 > 0.f ? e3 : NEG_SLOPE * e3;
        float w0 = exp2f(e0), w1 = exp2f(e1), w2 = exp2f(e2), w3 = exp2f(e3);
        a0 = fmaf(w0, u2f_lo(f0.x), a0); a1 = fmaf(w0, u2f_hi(f0.x), a1);
        a2 = fmaf(w0, u2f_lo(f0.y), a2); a3 = fmaf(w0, u2f_hi(f0.y), a3);
        a0 = fmaf(w1, u2f_lo(f1.x), a0); a1 = fmaf(w1, u2f_hi(f1.x), a1);
        a2 = fmaf(w1, u2f_lo(f1.y), a2); a3 = fmaf(w1, u2f_hi(f1.y), a3);
        a0 = fmaf(w2, u2f_lo(f2.x), a0); a1 = fmaf(w2, u2f_hi(f2.x), a1);
        a2 = fmaf(w2, u2f_lo(f2.y), a2); a3 = fmaf(w2, u2f_hi(f2.y), a3);
        a0 = fmaf(w3, u2f_lo(f3.x), a0); a1 = fmaf(w3, u2f_hi(f3.x), a1);
        a2 = fmaf(w3, u2f_lo(f3.y), a2); a3 = fmaf(w3, u2f_hi(f3.y), a3);
        sw += (w0 + w1) + (w2 + w3);
    }
    for (; j < cnt; ++j) {
        int sv = perm_src[start + j];
        float e = els[sv * 8 + h] + erh;
        e = e > 0.f ? e : NEG_SLOPE * e;
        float wv = exp2f(e);
        uint2 f = *(const uint2*)&ft[(size_t)sv * 256 + col];
        a0 = fmaf(wv, u2f_lo(f.x), a0);
        a1 = fmaf(wv, u2f_hi(f.x), a1);
        a2 = fmaf(wv, u2f_lo(f.y), a2);
        a3 = fmaf(wv, u2f_hi(f.y), a3);
        sw += wv;
    }

    // overflow fallback (practically always empty)
    int oc = *over_cnt;
    if (oc > 0) {
        oc = min(oc, OVER_CAP);
        for (int i = 0; i < oc; ++i) {
            int2 ed = over_edges[i];
            if (ed.y == n) {
                float e = els[ed.x * 8 + h] + erh;
                e = e > 0.f ? e : NEG_SLOPE * e;
                float wv = exp2f(e);
                uint2 f = *(const uint2*)&ft[(size_t)ed.x * 256 + col];
                a0 = fmaf(wv, u2f_lo(f.x), a0);
                a1 = fmaf(wv, u2f_hi(f.x), a1);
                a2 = fmaf(wv, u2f_lo(f.y), a2);
                a3 = fmaf(wv, u2f_hi(f.y), a3);
                sw += wv;
            }
        }
    }

    float inv = sw != 0.f ? 1.f / sw : 0.f;
    float4 b = *(const float4*)&bias[col];
    float4 o;
    o.x = a0 * inv + b.x;
    o.y = a1 * inv + b.y;
    o.z = a2 * inv + b.z;
    o.w = a3 * inv + b.w;
    *(float4*)&out[(size_t)n * 256 + col] = o;
}

// ---------------------------------------------------------------------------
extern "C" void kernel_launch(void* const* d_in, const int* in_sizes, int n_in,
                              void* d_out, int out_size, void* d_ws, size_t ws_size,
                              hipStream_t stream)
{
    const float* feat   = (const float*)d_in[0];
    const float* W      = (const float*)d_in[1];
    const float* attn_l = (const float*)d_in[2];
    const float* attn_r = (const float*)d_in[3];
    const float* bias   = (const float*)d_in[4];
    const int*   src    = (const int*)d_in[5];
    const int*   dst    = (const int*)d_in[6];
    const int N = in_sizes[0] / 256;
    const int E = in_sizes[5];
    const int nbuk = (N + BUK_NODES - 1) >> BUK_SHIFT;
    float* out = (float*)d_out;

    char* ws = (char*)d_ws;
    size_t off = 0;
    auto wsalloc = [&](size_t bytes) -> char* {
        char* p = ws + off;
        off = (off + bytes + 255) & ~(size_t)255;
        return p;
    };
    unsigned short* ft   = (unsigned short*)wsalloc((size_t)N * 256 * 2);       // 25.6 MB
    float* els           = (float*)wsalloc((size_t)N * 8 * 4);                  // 1.6 MB
    float* ers           = (float*)wsalloc((size_t)N * 8 * 4);                  // 1.6 MB
    int* deg             = (int*)wsalloc((size_t)N * 4);
    int* row_start       = (int*)wsalloc((size_t)N * 4);
    int* bucket_cnt      = (int*)wsalloc((size_t)nbuk * 4);
    int2* bucket_edges   = (int2*)wsalloc((size_t)nbuk * BUK_CAP * 8);          // 16 MB
    int* perm_src        = (int*)wsalloc((size_t)nbuk * BUK_CAP * 4);           // 8 MB
    int* over_cnt        = (int*)wsalloc(256);
    int2* over_edges     = (int2*)wsalloc((size_t)OVER_CAP * 8);
    unsigned short* whi  = (unsigned short*)wsalloc((size_t)65536 * 2);         // 128 KB
    unsigned short* wlo  = (unsigned short*)wsalloc((size_t)65536 * 2);         // 128 KB
    (void)ws_size; (void)n_in; (void)out_size;

    k_wsplit<<<32, 256, 0, stream>>>(W, whi, wlo);
    k_zero<<<(nbuk + 255) / 256, 256, 0, stream>>>(bucket_cnt, nbuk, over_cnt);
    k_bucket<<<(E + 4095) / 4096, 512, 0, stream>>>(src, dst, E, nbuk,
        bucket_cnt, bucket_edges, over_cnt, over_edges);
    k_gemm<<<(N + 63) / 64, 256, 0, stream>>>(feat, whi, wlo, attn_l, attn_r,
        ft, els, ers, N);
    k_csr<<<nbuk, 256, 0, stream>>>(bucket_edges, bucket_cnt, N, deg, row_start, perm_src);
    k_agg<<<(N + 3) / 4, 256, 0, stream>>>(ft, els, ers, row_start, deg, perm_src,
        bias, out, N, over_cnt, over_edges);
}

// Round 4
// 206.225 us; speedup vs baseline: 2.1171x; 1.2305x over previous
//
#include <hip/hip_runtime.h>

#define NEG_SLOPE 0.2f
#define LOG2E 1.44269504088896340736f

#define BUK_SHIFT 7
#define BUK_NODES 128
#define BUK_CAP   5120
#define MAX_NBUK  512
#define OVER_CAP  4096

typedef __attribute__((ext_vector_type(8))) short short8v;
typedef __attribute__((ext_vector_type(4))) float float4v;

__device__ __forceinline__ float bf2f(unsigned short u) {
    union { unsigned int u32; float f; } c;
    c.u32 = ((unsigned int)u) << 16;
    return c.f;
}
__device__ __forceinline__ unsigned short f2bf(float f) {
    union { float f; unsigned int u32; } c; c.f = f;
    unsigned int b = c.u32;
    b += 0x7fffu + ((b >> 16) & 1u);   // round-to-nearest-even
    return (unsigned short)(b >> 16);
}
// signed int8 from byte b of dword d -> float
__device__ __forceinline__ float i8f(unsigned int d, int b) {
    return (float)((int)(d << (24 - 8 * b)) >> 24);
}

// ---------------------------------------------------------------------------
// K0a: pre-split W (256x256 fp32) into hi/lo bf16 in MFMA B-fragment order:
// frag t = ((ks*16+ct)*64+lane), elem j -> W[ks*32+(lane>>4)*8+j][ct*16+(lane&15)].
// ---------------------------------------------------------------------------
__global__ __launch_bounds__(256) void k_wsplit(
    const float* __restrict__ W, unsigned short* __restrict__ whi,
    unsigned short* __restrict__ wlo)
{
    const int t = blockIdx.x * 256 + threadIdx.x;   // 0..8191
    const int lane = t & 63;
    const int ct = (t >> 6) & 15;
    const int ks = t >> 10;
    const int col = ct * 16 + (lane & 15);
    const int krow = ks * 32 + (lane >> 4) * 8;
#pragma unroll
    for (int j = 0; j < 8; ++j) {
        float v = W[(krow + j) * 256 + col];
        unsigned short h = f2bf(v);
        whi[(size_t)t * 8 + j] = h;
        wlo[(size_t)t * 8 + j] = f2bf(v - bf2f(h));
    }
}

// ---------------------------------------------------------------------------
// K1: ft = feat @ W via split-bf16 MFMA. 64 rows/block, 4 waves x 16 rows.
// B-frags staged in LDS per K-slice (shared by the 4 waves, L2-hot source).
// Fused epilogue: el/er (pre-scaled by log2 e) + per-(row,head) maxabs ->
// int8-quantized ft + scale. LDS reused for staging then byte transpose.
// ---------------------------------------------------------------------------
__global__ __launch_bounds__(256) void k_gemm(
    const float* __restrict__ A,
    const unsigned short* __restrict__ whi, const unsigned short* __restrict__ wlo,
    const float* __restrict__ attn_l, const float* __restrict__ attn_r,
    signed char* __restrict__ qft, float* __restrict__ pk,
    float* __restrict__ ers, int M)
{
    __shared__ char lds_raw[33792];          // 32KB stage | 4*16*264=16.5KB smq
    unsigned short* bst = (unsigned short*)lds_raw;   // [0,8192) hi, [8192,16384) lo
    const int tid = threadIdx.x;
    const int w = tid >> 6, lane = tid & 63;
    const int row0 = blockIdx.x * 64 + w * 16;
    const int arow = row0 + (lane & 15);
    const bool aval = arow < M;
    const float* ap = A + (size_t)arow * 256 + (lane >> 4) * 8;

    float4v acc[16];
#pragma unroll
    for (int ct = 0; ct < 16; ++ct) acc[ct] = (float4v){0.f, 0.f, 0.f, 0.f};

    for (int ks = 0; ks < 8; ++ks) {
        __syncthreads();   // previous iteration's readers done
        {
            const uint4* srchi = (const uint4*)(whi + ks * 8192);
            const uint4* srclo = (const uint4*)(wlo + ks * 8192);
            uint4* dsthi = (uint4*)bst;
            uint4* dstlo = (uint4*)(bst + 8192);
#pragma unroll
            for (int p = 0; p < 4; ++p) {
                dsthi[p * 256 + tid] = srchi[p * 256 + tid];
                dstlo[p * 256 + tid] = srclo[p * 256 + tid];
            }
        }
        float av[8];
        if (aval) {
            float4 a0 = *(const float4*)(ap + ks * 32);
            float4 a1 = *(const float4*)(ap + ks * 32 + 4);
            av[0] = a0.x; av[1] = a0.y; av[2] = a0.z; av[3] = a0.w;
            av[4] = a1.x; av[5] = a1.y; av[6] = a1.z; av[7] = a1.w;
        } else {
#pragma unroll
            for (int j = 0; j < 8; ++j) av[j] = 0.f;
        }
        short8v ahi, alo;
#pragma unroll
        for (int j = 0; j < 8; ++j) {
            unsigned short h = f2bf(av[j]);
            ahi[j] = (short)h;
            alo[j] = (short)f2bf(av[j] - bf2f(h));
        }
        __syncthreads();   // stage visible
#pragma unroll
        for (int ct = 0; ct < 16; ++ct) {
            short8v bhi = *(const short8v*)(bst + ct * 512 + lane * 8);
            short8v blo = *(const short8v*)(bst + 8192 + ct * 512 + lane * 8);
            acc[ct] = __builtin_amdgcn_mfma_f32_16x16x32_bf16(ahi, bhi, acc[ct], 0, 0, 0);
            acc[ct] = __builtin_amdgcn_mfma_f32_16x16x32_bf16(alo, bhi, acc[ct], 0, 0, 0);
            acc[ct] = __builtin_amdgcn_mfma_f32_16x16x32_bf16(ahi, blo, acc[ct], 0, 0, 0);
        }
    }

    __syncthreads();   // done with bst; reuse LDS for byte transpose
    char* smq = lds_raw + (size_t)w * 4224;     // [16 rows][264]
    const int c = lane & 15, g = lane >> 4;

    // el/er + maxabs + int8 quantize. C/D layout: col=lane&15, row=g*4+reg.
#pragma unroll
    for (int reg = 0; reg < 4; ++reg) {
        const int row = row0 + g * 4 + reg;
#pragma unroll
        for (int h = 0; h < 8; ++h) {
            float v0 = acc[2 * h][reg], v1 = acc[2 * h + 1][reg];
            float pl = v0 * attn_l[h * 32 + c] + v1 * attn_l[h * 32 + 16 + c];
            float pr = v0 * attn_r[h * 32 + c] + v1 * attn_r[h * 32 + 16 + c];
            float mx = fmaxf(fabsf(v0), fabsf(v1));
#pragma unroll
            for (int off = 1; off <= 8; off <<= 1) {
                pl += __shfl_xor(pl, off);
                pr += __shfl_xor(pr, off);
                mx = fmaxf(mx, __shfl_xor(mx, off));
            }
            float inv = mx > 0.f ? 127.f / mx : 0.f;
            int q0 = (int)rintf(v0 * inv);
            int q1 = (int)rintf(v1 * inv);
            smq[(g * 4 + reg) * 264 + h * 32 + c]      = (signed char)q0;
            smq[(g * 4 + reg) * 264 + h * 32 + 16 + c] = (signed char)q1;
            if (c == 0 && row < M) {
                pk[(row * 8 + h) * 2]     = pl * LOG2E;
                pk[(row * 8 + h) * 2 + 1] = mx * (1.f / 127.f);
                ers[row * 8 + h]          = pr * LOG2E;
            }
        }
    }
    __syncthreads();
#pragma unroll
    for (int it = 0; it < 16; ++it) {
        int grow = row0 + it;
        if (grow < M)
            *(int*)(qft + (size_t)grow * 256 + lane * 4) =
                *(const int*)(smq + it * 264 + lane * 4);
    }
}

// ---------------------------------------------------------------------------
// K0b: zero bucket counters + overflow counter.
// ---------------------------------------------------------------------------
__global__ __launch_bounds__(256) void k_zero(int* __restrict__ bucket_cnt, int nbuk,
                                              int* __restrict__ over_cnt)
{
    int i = blockIdx.x * 256 + threadIdx.x;
    if (i < nbuk) bucket_cnt[i] = 0;
    if (i == 0) *over_cnt = 0;
}

// ---------------------------------------------------------------------------
// K3a: two-level binning — (src,dst) pairs into per-bucket regions.
// ---------------------------------------------------------------------------
__global__ __launch_bounds__(512) void k_bucket(
    const int* __restrict__ src, const int* __restrict__ dst, int E, int nbuk,
    int* __restrict__ bucket_cnt, int2* __restrict__ bucket_edges,
    int* __restrict__ over_cnt, int2* __restrict__ over_edges)
{
    __shared__ int lhist[MAX_NBUK];
    __shared__ int lbase[MAX_NBUK];
    __shared__ int lcur[MAX_NBUK];
    const int tid = threadIdx.x;
    for (int i = tid; i < nbuk; i += 512) lhist[i] = 0;
    __syncthreads();

    const int e0 = blockIdx.x * 4096;
#pragma unroll
    for (int p = 0; p < 8; ++p) {
        int e = e0 + p * 512 + tid;
        if (e < E) atomicAdd(&lhist[dst[e] >> BUK_SHIFT], 1);
    }
    __syncthreads();
    for (int i = tid; i < nbuk; i += 512) {
        int cc = lhist[i];
        lbase[i] = (cc > 0) ? atomicAdd(&bucket_cnt[i], cc) : 0;
        lcur[i] = 0;
    }
    __syncthreads();
#pragma unroll
    for (int p = 0; p < 8; ++p) {
        int e = e0 + p * 512 + tid;
        if (e < E) {
            int d = dst[e];
            int s = src[e];
            int bin = d >> BUK_SHIFT;
            int r = atomicAdd(&lcur[bin], 1);
            int pos = lbase[bin] + r;
            if (pos < BUK_CAP) {
                bucket_edges[(size_t)bin * BUK_CAP + pos] = make_int2(s, d);
            } else {
                int oi = atomicAdd(over_cnt, 1);
                if (oi < OVER_CAP) over_edges[oi] = make_int2(s, d);
            }
        }
    }
}

// ---------------------------------------------------------------------------
// K3b: per-bucket CSR finalize.
// ---------------------------------------------------------------------------
__global__ __launch_bounds__(256) void k_csr(
    const int2* __restrict__ bucket_edges, const int* __restrict__ bucket_cnt,
    int N, int* __restrict__ deg, int* __restrict__ row_start,
    int* __restrict__ perm_src)
{
    __shared__ int hist[BUK_NODES];
    __shared__ int pfx[BUK_NODES];
    __shared__ int curs[BUK_NODES];
    const int bu = blockIdx.x;
    const int tid = threadIdx.x;
    const int cnt = min(bucket_cnt[bu], BUK_CAP);
    const int node0 = bu << BUK_SHIFT;
    if (tid < BUK_NODES) hist[tid] = 0;
    __syncthreads();
    for (int i = tid; i < cnt; i += 256) {
        int2 ed = bucket_edges[(size_t)bu * BUK_CAP + i];
        atomicAdd(&hist[ed.y & (BUK_NODES - 1)], 1);
    }
    __syncthreads();
    if (tid == 0) {
        int s = 0;
#pragma unroll
        for (int i = 0; i < BUK_NODES; ++i) { pfx[i] = s; s += hist[i]; }
    }
    __syncthreads();
    if (tid < BUK_NODES) {
        int n = node0 + tid;
        if (n < N) {
            deg[n] = hist[tid];
            row_start[n] = bu * BUK_CAP + pfx[tid];
        }
        curs[tid] = pfx[tid];
    }
    __syncthreads();
    for (int i = tid; i < cnt; i += 256) {
        int2 ed = bucket_edges[(size_t)bu * BUK_CAP + i];
        int r = atomicAdd(&curs[ed.y & (BUK_NODES - 1)], 1);
        perm_src[(size_t)bu * BUK_CAP + r] = ed.x;
    }
}

// ---------------------------------------------------------------------------
// K4: per-dst aggregation, int8 ft. One wave per node; lane owns 4 cols
// (1 dword gather/edge). pk[src,h] = (el*log2e, scale) as float2;
// ws = exp2(lrelu(el+er)) * scale; a += ws * q. Src ids prefetched 1 iter
// ahead to break the index->gather dependence chain.
// ---------------------------------------------------------------------------
__global__ __launch_bounds__(256) void k_agg(
    const signed char* __restrict__ qft,
    const float* __restrict__ pk, const float* __restrict__ ers,
    const int* __restrict__ row_start, const int* __restrict__ deg,
    const int* __restrict__ perm_src,
    const float* __restrict__ bias, float* __restrict__ out, int N,
    const int* __restrict__ over_cnt, const int2* __restrict__ over_edges)
{
    const int tid = threadIdx.x;
    const int lane = tid & 63;
    const int n = blockIdx.x * 4 + (tid >> 6);
    if (n >= N) return;
    const int h = lane >> 3;
    const int colb = lane * 4;            // byte offset within 256-byte row
    const float erh = ers[n * 8 + h];
    const int start = row_start[n];
    const int cnt = deg[n];

    float a0 = 0.f, a1 = 0.f, a2 = 0.f, a3 = 0.f, sw = 0.f;

    int j = 0;
    int s0 = 0, s1 = 0, s2 = 0, s3 = 0;
    if (cnt >= 4) {
        s0 = perm_src[start + 0]; s1 = perm_src[start + 1];
        s2 = perm_src[start + 2]; s3 = perm_src[start + 3];
    }
    for (; j + 3 < cnt; ) {
        const int v0 = s0, v1 = s1, v2 = s2, v3 = s3;
        j += 4;
        if (j + 3 < cnt) {      // prefetch next quad while current is processed
            s0 = perm_src[start + j + 0]; s1 = perm_src[start + j + 1];
            s2 = perm_src[start + j + 2]; s3 = perm_src[start + j + 3];
        }
        float2 g0 = *(const float2*)&pk[(v0 * 8 + h) * 2];
        float2 g1 = *(const float2*)&pk[(v1 * 8 + h) * 2];
        float2 g2 = *(const float2*)&pk[(v2 * 8 + h) * 2];
        float2 g3 = *(const float2*)&pk[(v3 * 8 + h) * 2];
        unsigned int d0 = *(const unsigned int*)&qft[(size_t)v0 * 256 + colb];
        unsigned int d1 = *(const unsigned int*)&qft[(size_t)v1 * 256 + colb];
        unsigned int d2 = *(const unsigned int*)&qft[(size_t)v2 * 256 + colb];
        unsigned int d3 = *(const unsigned int*)&qft[(size_t)v3 * 256 + colb];
        float e0 = g0.x + erh, e1 = g1.x + erh, e2 = g2.x + erh, e3 = g3.x + erh;
        e0 = e0 > 0.f ? e0 : NEG_SLOPE * e0;
        e1 = e1 > 0.f ? e1 : NEG_SLOPE * e1;
        e2 = e2 > 0.f ? e2 : NEG_SLOPE * e2;
        e3 = e3 > 0.f ? e3 : NEG_SLOPE * e3;
        float w0 = exp2f(e0), w1 = exp2f(e1), w2 = exp2f(e2), w3 = exp2f(e3);
        float ws0 = w0 * g0.y, ws1 = w1 * g1.y, ws2 = w2 * g2.y, ws3 = w3 * g3.y;
        a0 = fmaf(ws0, i8f(d0, 0), a0); a1 = fmaf(ws0, i8f(d0, 1), a1);
        a2 = fmaf(ws0, i8f(d0, 2), a2); a3 = fmaf(ws0, i8f(d0, 3), a3);
        a0 = fmaf(ws1, i8f(d1, 0), a0); a1 = fmaf(ws1, i8f(d1, 1), a1);
        a2 = fmaf(ws1, i8f(d1, 2), a2); a3 = fmaf(ws1, i8f(d1, 3), a3);
        a0 = fmaf(ws2, i8f(d2, 0), a0); a1 = fmaf(ws2, i8f(d2, 1), a1);
        a2 = fmaf(ws2, i8f(d2, 2), a2); a3 = fmaf(ws2, i8f(d2, 3), a3);
        a0 = fmaf(ws3, i8f(d3, 0), a0); a1 = fmaf(ws3, i8f(d3, 1), a1);
        a2 = fmaf(ws3, i8f(d3, 2), a2); a3 = fmaf(ws3, i8f(d3, 3), a3);
        sw += (w0 + w1) + (w2 + w3);
    }
    for (; j < cnt; ++j) {
        int sv = perm_src[start + j];
        float2 g = *(const float2*)&pk[(sv * 8 + h) * 2];
        float e = g.x + erh;
        e = e > 0.f ? e : NEG_SLOPE * e;
        float wv = exp2f(e);
        float ws = wv * g.y;
        unsigned int d = *(const unsigned int*)&qft[(size_t)sv * 256 + colb];
        a0 = fmaf(ws, i8f(d, 0), a0);
        a1 = fmaf(ws, i8f(d, 1), a1);
        a2 = fmaf(ws, i8f(d, 2), a2);
        a3 = fmaf(ws, i8f(d, 3), a3);
        sw += wv;
    }

    // overflow fallback (practically always empty)
    int oc = *over_cnt;
    if (oc > 0) {
        oc = min(oc, OVER_CAP);
        for (int i = 0; i < oc; ++i) {
            int2 ed = over_edges[i];
            if (ed.y == n) {
                float2 g = *(const float2*)&pk[(ed.x * 8 + h) * 2];
                float e = g.x + erh;
                e = e > 0.f ? e : NEG_SLOPE * e;
                float wv = exp2f(e);
                float ws = wv * g.y;
                unsigned int d = *(const unsigned int*)&qft[(size_t)ed.x * 256 + colb];
                a0 = fmaf(ws, i8f(d, 0), a0);
                a1 = fmaf(ws, i8f(d, 1), a1);
                a2 = fmaf(ws, i8f(d, 2), a2);
                a3 = fmaf(ws, i8f(d, 3), a3);
                sw += wv;
            }
        }
    }

    float inv = sw != 0.f ? 1.f / sw : 0.f;
    float4 b = *(const float4*)&bias[colb];
    float4 o;
    o.x = a0 * inv + b.x;
    o.y = a1 * inv + b.y;
    o.z = a2 * inv + b.z;
    o.w = a3 * inv + b.w;
    *(float4*)&out[(size_t)n * 256 + colb] = o;
}

// ---------------------------------------------------------------------------
extern "C" void kernel_launch(void* const* d_in, const int* in_sizes, int n_in,
                              void* d_out, int out_size, void* d_ws, size_t ws_size,
                              hipStream_t stream)
{
    const float* feat   = (const float*)d_in[0];
    const float* W      = (const float*)d_in[1];
    const float* attn_l = (const float*)d_in[2];
    const float* attn_r = (const float*)d_in[3];
    const float* bias   = (const float*)d_in[4];
    const int*   src    = (const int*)d_in[5];
    const int*   dst    = (const int*)d_in[6];
    const int N = in_sizes[0] / 256;
    const int E = in_sizes[5];
    const int nbuk = (N + BUK_NODES - 1) >> BUK_SHIFT;
    float* out = (float*)d_out;

    char* ws = (char*)d_ws;
    size_t off = 0;
    auto wsalloc = [&](size_t bytes) -> char* {
        char* p = ws + off;
        off = (off + bytes + 255) & ~(size_t)255;
        return p;
    };
    signed char* qft     = (signed char*)wsalloc((size_t)N * 256);              // 12.8 MB
    float* pk            = (float*)wsalloc((size_t)N * 16 * 4);                 // 3.2 MB (el,scale)
    float* ers           = (float*)wsalloc((size_t)N * 8 * 4);                  // 1.6 MB
    int* deg             = (int*)wsalloc((size_t)N * 4);
    int* row_start       = (int*)wsalloc((size_t)N * 4);
    int* bucket_cnt      = (int*)wsalloc((size_t)nbuk * 4);
    int2* bucket_edges   = (int2*)wsalloc((size_t)nbuk * BUK_CAP * 8);          // 16 MB
    int* perm_src        = (int*)wsalloc((size_t)nbuk * BUK_CAP * 4);           // 8 MB
    int* over_cnt        = (int*)wsalloc(256);
    int2* over_edges     = (int2*)wsalloc((size_t)OVER_CAP * 8);
    unsigned short* whi  = (unsigned short*)wsalloc((size_t)65536 * 2);         // 128 KB
    unsigned short* wlo  = (unsigned short*)wsalloc((size_t)65536 * 2);         // 128 KB
    (void)ws_size; (void)n_in; (void)out_size;

    k_wsplit<<<32, 256, 0, stream>>>(W, whi, wlo);
    k_zero<<<(nbuk + 255) / 256, 256, 0, stream>>>(bucket_cnt, nbuk, over_cnt);
    k_bucket<<<(E + 4095) / 4096, 512, 0, stream>>>(src, dst, E, nbuk,
        bucket_cnt, bucket_edges, over_cnt, over_edges);
    k_gemm<<<(N + 63) / 64, 256, 0, stream>>>(feat, whi, wlo, attn_l, attn_r,
        qft, pk, ers, N);
    k_csr<<<nbuk, 256, 0, stream>>>(bucket_edges, bucket_cnt, N, deg, row_start, perm_src);
    k_agg<<<(N + 3) / 4, 256, 0, stream>>>(qft, pk, ers, row_start, deg, perm_src,
        bias, out, N, over_cnt, over_edges);
}